// Round 6
// baseline (206.900 us; speedup 1.0000x reference)
//
#include <hip/hip_runtime.h>
#include <hip/hip_cooperative_groups.h>
#include <math.h>

namespace cg = cooperative_groups;

#define BB 8
#define NN 2000
#define CC 81
#define MAXI 100
#define WPB 32              // u64 words per kept-bitmask (2048 bits >= 2000)
#define MCAP 512            // per-class member cap (observed ~25; 20-sigma safe)

static constexpr float kMinConf = 0.7f;
static constexpr float kNmsThr  = 0.3f;

// ---------------- workspace layout (bytes) ----------------
// boxes  : [0,       256000)   BN*4 f32
// key    : [256000,  320000)   BN f32  (score if valid else -inf)
// cls    : [320000,  384000)   BN i32
// sboxes : [384000,  640000)   BN*4 f32 (sorted)
// sscore : [640000,  704000)   BN f32   (sorted key)
// scls   : [704000,  768000)   BN i32   (sorted)
// kw     : [768000,  770048)   B*32 u64 kept bits (zeroed in phase 1)
// ckey   : [770048,  898048)   BN u64 composite sort key

__device__ __forceinline__ unsigned int mono_u32(float f) {
    unsigned int u = __float_as_uint(f);
    return (u & 0x80000000u) ? ~u : (u | 0x80000000u);   // order-preserving
}

__device__ __forceinline__ bool iou_gt_thr(float4 a, float aarea, float4 t) {
    float iy1 = fmaxf(a.x, t.x), ix1 = fmaxf(a.y, t.y);
    float iy2 = fminf(a.z, t.z), ix2 = fminf(a.w, t.w);
    float inter = fmaxf(iy2 - iy1, 0.f) * fmaxf(ix2 - ix1, 0.f);
    float tarea = (t.z - t.x) * (t.w - t.y);
    float uni = fmaxf(aarea + tarea - inter, 1e-12f);
    return inter > kNmsThr * uni;
}

// Single cooperative kernel: 256 blocks x 256 threads (1 block/CU).
// Phase1 refine -> sync -> Phase2 rank-sort -> sync -> Phase3 per-class NMS
// -> sync -> Phase4 emit. LDS: 16K (keys) + 1K (part) + 42K (NMS slices) = 59K.
__global__ void __launch_bounds__(256) kfused(
        const float* __restrict__ rois,
        const float* __restrict__ probs,
        const float* __restrict__ deltas,
        float* __restrict__ boxes,
        float* __restrict__ key,
        int* __restrict__ cls,
        unsigned long long* __restrict__ ckey,
        unsigned long long* __restrict__ kw,
        float* __restrict__ sboxes,
        float* __restrict__ sscore,
        int* __restrict__ scls,
        float* __restrict__ out) {
    cg::grid_group grid = cg::this_grid();

    __shared__ ulonglong2 lk2[NN / 2];          // 16000 B (phase 2)
    __shared__ int part[4][64];                 //  1024 B (phase 2)
    __shared__ int    midx3[4][MCAP];           //  8192 B (phase 3)
    __shared__ float4 mbox3[4][MCAP];           // 32768 B (phase 3)
    __shared__ unsigned char mkept3[4][MCAP];   //  2048 B (phase 3)

    const int tid = threadIdx.x;
    const int blk = blockIdx.x;
    const int l = tid & 63;
    const int wv = tid >> 6;                    // wave in block 0..3
    const int gwave = blk * 4 + wv;             // 0..1023

    // ================= phase 1: argmax + refine =================
    if (blk == 0) kw[tid] = 0ull;               // 256 words == BB*WPB

    for (int wid = gwave; wid < BB * NN; wid += 1024) {
        const float* p = probs + (size_t)wid * CC;
        float v1 = p[l];                        // l < 64 < 81 always valid
        int   i1 = l;
        int   c2 = l + 64;
        float v2 = (c2 < CC) ? p[c2] : -1.0f;   // probs in [0,1)
        float bv; int bi;
        if (v2 > v1) { bv = v2; bi = c2; } else { bv = v1; bi = i1; }

        #pragma unroll
        for (int off = 32; off; off >>= 1) {
            float ov = __shfl_xor(bv, off);
            int   oi = __shfl_xor(bi, off);
            if (ov > bv || (ov == bv && oi < bi)) { bv = ov; bi = oi; }
        }

        if (l == 0) {
            const float4 dl = *(const float4*)(deltas + ((size_t)wid * CC + bi) * 4);
            float dy = dl.x * 0.1f, dx = dl.y * 0.1f, dh = dl.z * 0.2f, dw = dl.w * 0.2f;
            const float4 r = *(const float4*)(rois + (size_t)wid * 4);
            float y1 = r.x, x1 = r.y, y2 = r.z, x2 = r.w;
            float h = y2 - y1, w = x2 - x1;
            float cy = y1 + 0.5f * h + dy * h;
            float cx = x1 + 0.5f * w + dx * w;
            float h2 = h * expf(dh);
            float w2 = w * expf(dw);
            float oy1 = fminf(fmaxf(cy - 0.5f * h2, 0.f), 1.f);
            float ox1 = fminf(fmaxf(cx - 0.5f * w2, 0.f), 1.f);
            float oy2 = fminf(fmaxf(cy + 0.5f * h2, 0.f), 1.f);
            float ox2 = fminf(fmaxf(cx + 0.5f * w2, 0.f), 1.f);
            bool valid = (bi > 0) && (bv >= kMinConf);
            float kv = valid ? bv : -INFINITY;
            float4 bx; bx.x = oy1; bx.y = ox1; bx.z = oy2; bx.w = ox2;
            ((float4*)boxes)[wid] = bx;
            key[wid] = kv;
            cls[wid] = bi;
            unsigned int i_in_b = (unsigned int)(wid % NN);
            ckey[wid] = ((unsigned long long)mono_u32(kv) << 32) | (unsigned int)(~i_in_b);
        }
    }

    __threadfence();
    grid.sync();

    // ================= phase 2: rank sort (block = 64 i's of one batch) ====
    {
        unsigned long long* lkey = (unsigned long long*)lk2;
        const int b = blk >> 5;                 // 32 blocks per batch
        const int i0 = (blk & 31) * 64;

        const ulonglong2* ck2 = (const ulonglong2*)(ckey + (size_t)b * NN);
        for (int t = tid; t < NN / 2; t += 256) lk2[t] = ck2[t];
        __syncthreads();

        const int i = i0 + l;
        const unsigned long long Ki = lkey[(i < NN) ? i : (NN - 1)];

        int r = 0;
        const int j0 = wv * 500;
        #pragma unroll 4
        for (int j = j0; j < j0 + 500; ++j) r += (int)(lkey[j] > Ki);
        part[wv][l] = r;
        __syncthreads();

        if (tid < 64) {
            int i2 = i0 + tid;
            if (i2 < NN) {
                int rank = part[0][tid] + part[1][tid] + part[2][tid] + part[3][tid];
                int src = b * NN + i2;
                int dst = b * NN + rank;
                ((float4*)sboxes)[dst] = ((const float4*)boxes)[src];
                sscore[dst] = key[src];
                scls[dst] = cls[src];
            }
        }
    }

    __threadfence();
    grid.sync();

    // ================= phase 3: per-(batch,class) greedy NMS, wave-per-job =
    {
        const int p = gwave;
        if (p < BB * (CC - 1)) {
            const int b = p / (CC - 1);
            const int c = p % (CC - 1) + 1;     // classes 1..80

            const float4* bxs = (const float4*)sboxes + (size_t)b * NN;
            const float* ss = sscore + (size_t)b * NN;
            const int* cl = scls + (size_t)b * NN;

            int*            midx  = midx3[wv];
            float4*         mbox  = mbox3[wv];
            unsigned char*  mkept = mkept3[wv];

            // collect members of class c in sorted order (double-buffered scan)
            int cnt = 0;
            float sc_cur = ss[l];
            int   cl_cur = cl[l];
            constexpr int NCH = (NN + 63) / 64;
            for (int ch = 0; ch < NCH; ++ch) {
                int i_nxt = (ch + 1) * 64 + l;
                float sc_nxt = 0.f; int cl_nxt = -1;
                if (ch + 1 < NCH && i_nxt < NN) { sc_nxt = ss[i_nxt]; cl_nxt = cl[i_nxt]; }
                int i = ch * 64 + l;
                bool pred = (i < NN) && (cl_cur == c) && (sc_cur != -INFINITY);
                unsigned long long mask = __ballot(pred);
                if (pred) {
                    int pos = cnt + __popcll(mask & ((1ull << l) - 1ull));
                    if (pos < MCAP) { midx[pos] = i; mbox[pos] = bxs[i]; }
                }
                cnt += __popcll(mask);
                sc_cur = sc_nxt; cl_cur = cl_nxt;
            }
            if (cnt > MCAP) cnt = MCAP;

            // greedy NMS over members, 64 at a time, ballot fixpoint (== greedy)
            for (int q0 = 0; q0 < cnt; q0 += 64) {
                int m = q0 + l;
                bool active = (m < cnt);
                float4 a = mbox[active ? m : 0];
                float aarea = (a.z - a.x) * (a.w - a.y);

                bool presup = false;
                for (int t = 0; t < q0; ++t) {
                    if (mkept[t] && iou_gt_thr(a, aarea, mbox[t])) presup = true;
                }

                unsigned long long colmask = 0ull;
                int tend = min(64, cnt - q0);
                for (int t = 0; t < tend; ++t) {
                    float4 tb = mbox[q0 + t];           // wave-uniform LDS read
                    if (t < l && iou_gt_thr(a, aarea, tb)) colmask |= (1ull << t);
                }

                bool pre = active && !presup;
                unsigned long long kept = __ballot(pre);
                while (true) {
                    bool alive0 = pre && ((colmask & kept) == 0ull);
                    unsigned long long k2m = __ballot(alive0);
                    if (k2m == kept) break;
                    kept = k2m;
                }
                bool alive = pre && ((colmask & kept) == 0ull);
                if (active) {
                    mkept[m] = alive ? 1 : 0;
                    if (alive) {
                        int j = midx[m];
                        atomicOr(&kw[b * WPB + (j >> 6)], 1ull << (j & 63));
                    }
                }
            }
        }
    }

    __threadfence();
    grid.sync();

    // ================= phase 4: emit first 100 kept rows (blocks 0..7) =====
    if (blk < BB && tid < 64) {
        const int b = blk;
        unsigned long long keep = (l < WPB) ? kw[b * WPB + l] : 0ull;

        int cnt = __popcll(keep);
        int base = 0, total = 0;
        for (int w2 = 0; w2 < 32; ++w2) {
            int c2 = __shfl(cnt, w2);
            if (w2 < l) base += c2;
            total += c2;
        }

        if (l < 32) {
            unsigned long long kk = keep;
            int r = base;
            while (kk) {
                int k = __builtin_ctzll(kk);
                kk &= kk - 1;
                if (r < MAXI) {
                    int j = l * 64 + k;
                    float4 bx = ((const float4*)sboxes)[b * NN + j];
                    float* o = out + ((size_t)b * MAXI + r) * 6;
                    o[0] = bx.x; o[1] = bx.y; o[2] = bx.z; o[3] = bx.w;
                    o[4] = (float)scls[b * NN + j];
                    o[5] = sscore[b * NN + j];
                }
                ++r;
            }
        }
        for (int r = total + l; r < MAXI; r += 64) {
            float* o = out + ((size_t)b * MAXI + r) * 6;
            #pragma unroll
            for (int q = 0; q < 6; ++q) o[q] = 0.f;
        }
    }
}

extern "C" void kernel_launch(void* const* d_in, const int* in_sizes, int n_in,
                              void* d_out, int out_size, void* d_ws, size_t ws_size,
                              hipStream_t stream) {
    const float* rois   = (const float*)d_in[0];
    const float* probs  = (const float*)d_in[1];
    const float* deltas = (const float*)d_in[2];
    float* outp = (float*)d_out;

    char* ws = (char*)d_ws;
    float* boxes  = (float*)(ws + 0);
    float* key    = (float*)(ws + 256000);
    int*   cls    = (int*)  (ws + 320000);
    float* sboxes = (float*)(ws + 384000);
    float* sscore = (float*)(ws + 640000);
    int*   scls   = (int*)  (ws + 704000);
    unsigned long long* kw   = (unsigned long long*)(ws + 768000);
    unsigned long long* ckey = (unsigned long long*)(ws + 770048);

    void* args[] = {
        (void*)&rois, (void*)&probs, (void*)&deltas,
        (void*)&boxes, (void*)&key, (void*)&cls,
        (void*)&ckey, (void*)&kw,
        (void*)&sboxes, (void*)&sscore, (void*)&scls,
        (void*)&outp
    };
    hipLaunchCooperativeKernel((void*)kfused, dim3(256), dim3(256), args, 0, stream);
}

// Round 7
// 99.945 us; speedup vs baseline: 2.0701x; 2.0701x over previous
//
#include <hip/hip_runtime.h>
#include <math.h>

#define BB 8
#define NN 2000
#define CC 81
#define MAXI 100
#define MCLS 128            // per-class member cap (observed ~25, ~20-sigma safe)

static constexpr float kMinConf = 0.7f;
static constexpr float kNmsThr  = 0.3f;

// ---------------- workspace layout (bytes) ----------------
// boxes : [0,      256000)  BN*4 f32 (refined, clipped)
// sc    : [256000, 320000)  BN f32   (raw max score)
// cls   : [320000, 384000)  BN i32   (argmax class; 0 if invalid)

// ---- kA: wave-per-ROI argmax + box refine (coalesced probs reads) ----
__global__ void kA_refine(const float* __restrict__ rois,
                          const float* __restrict__ probs,
                          const float* __restrict__ deltas,
                          float* __restrict__ boxes,
                          float* __restrict__ sc,
                          int* __restrict__ cls) {
    int gtid = blockIdx.x * blockDim.x + threadIdx.x;
    int wid = gtid >> 6;                // one wave per ROI
    int l = gtid & 63;

    const float* p = probs + (size_t)wid * CC;
    float v1 = p[l];                    // l < 64 < 81 always valid
    int   i1 = l;
    int   c2 = l + 64;
    float v2 = (c2 < CC) ? p[c2] : -1.0f;   // probs in [0,1)
    float bv; int bi;
    if (v2 > v1) { bv = v2; bi = c2; } else { bv = v1; bi = i1; }

    #pragma unroll
    for (int off = 32; off; off >>= 1) {
        float ov = __shfl_xor(bv, off);
        int   oi = __shfl_xor(bi, off);
        if (ov > bv || (ov == bv && oi < bi)) { bv = ov; bi = oi; }
    }

    if (l == 0) {
        const float4 dl = *(const float4*)(deltas + ((size_t)wid * CC + bi) * 4);
        float dy = dl.x * 0.1f, dx = dl.y * 0.1f, dh = dl.z * 0.2f, dw = dl.w * 0.2f;
        const float4 r = *(const float4*)(rois + (size_t)wid * 4);
        float y1 = r.x, x1 = r.y, y2 = r.z, x2 = r.w;
        float h = y2 - y1, w = x2 - x1;
        float cy = y1 + 0.5f * h + dy * h;
        float cx = x1 + 0.5f * w + dx * w;
        float h2 = h * expf(dh);
        float w2 = w * expf(dw);
        float oy1 = fminf(fmaxf(cy - 0.5f * h2, 0.f), 1.f);
        float ox1 = fminf(fmaxf(cx - 0.5f * w2, 0.f), 1.f);
        float oy2 = fminf(fmaxf(cy + 0.5f * h2, 0.f), 1.f);
        float ox2 = fminf(fmaxf(cx + 0.5f * w2, 0.f), 1.f);
        bool valid = (bi > 0) && (bv >= kMinConf);
        float4 bx; bx.x = oy1; bx.y = ox1; bx.z = oy2; bx.w = ox2;
        ((float4*)boxes)[wid] = bx;
        sc[wid] = bv;
        cls[wid] = valid ? bi : 0;      // cls==0 encodes "invalid"
    }
}

__device__ __forceinline__ bool iou_gt_thr(float4 a, float aarea, float4 t) {
    float iy1 = fmaxf(a.x, t.x), ix1 = fmaxf(a.y, t.y);
    float iy2 = fminf(a.z, t.z), ix2 = fminf(a.w, t.w);
    float inter = fmaxf(iy2 - iy1, 0.f) * fmaxf(ix2 - ix1, 0.f);
    float tarea = (t.z - t.x) * (t.w - t.y);
    float uni = fmaxf(aarea + tarea - inter, 1e-12f);
    return inter > kNmsThr * uni;
}

// member key: (score bits << 32) | ~idx  — valid scores are positive floats so
// uint compare == float compare; key desc == (score desc, idx asc) == reference
// stable order. idx recoverable as ~(u32)key.
__device__ __forceinline__ unsigned long long mkey(float s, int i) {
    return ((unsigned long long)__float_as_uint(s) << 32) | (unsigned int)(~(unsigned int)i);
}

// ---- kB: one block per batch. Stage batch in LDS; per-wave per-class greedy
// NMS (member collect -> in-wave rank sort -> ballot fixpoint == greedy);
// then per-batch top-100 by rank-count over kept keys. No global sort needed.
__global__ void __launch_bounds__(1024) kB_nms(
        const float* __restrict__ boxes,
        const float* __restrict__ sc,
        const int* __restrict__ cls,
        float* __restrict__ out) {
    __shared__ float4 lbox[NN];                       // 32000 B
    __shared__ float  lsc[NN];                        //  8000 B
    __shared__ unsigned char lcl[2048];               //  2048 B
    __shared__ unsigned long long mk[16][MCLS];       // 16384 B (reused as klist)
    __shared__ unsigned char keptflag[2048];          //  2048 B
    __shared__ int Tcnt;

    const int b = blockIdx.x;
    const int tid = threadIdx.x;
    const int wv = tid >> 6;            // wave 0..15
    const int l = tid & 63;

    // ---- stage batch ----
    for (int i = tid; i < NN; i += 1024) {
        lbox[i] = ((const float4*)boxes)[b * NN + i];
        lsc[i]  = sc[b * NN + i];
        lcl[i]  = (unsigned char)cls[b * NN + i];
    }
    for (int i = tid; i < 2048; i += 1024) keptflag[i] = 0;
    if (tid == 0) Tcnt = 0;
    __syncthreads();

    // ---- per-class greedy NMS: wave wv handles classes 1+wv, 17+wv, ... ----
    for (int k = 0; k < 5; ++k) {
        const int c = 1 + wv + 16 * k;                // 1..80

        // collect members (class == c) in row order
        int cnt = 0;
        for (int ch = 0; ch < 32; ++ch) {
            int i = ch * 64 + l;
            bool pred = (i < NN) && (lcl[i] == (unsigned char)c);
            unsigned long long mask = __ballot(pred);
            if (pred) {
                int pos = cnt + __popcll(mask & ((1ull << l) - 1ull));
                if (pos < MCLS) mk[wv][pos] = mkey(lsc[i], i);
            }
            cnt += __popcll(mask);
        }
        if (cnt > MCLS) cnt = MCLS;

        // in-wave stable rank sort of members by key desc (in place; lockstep
        // wave => all reads of the rank loops complete before the scatters)
        {
            unsigned long long Ka = (l < cnt) ? mk[wv][l] : 0ull;
            unsigned long long Kb = (64 + l < cnt) ? mk[wv][64 + l] : 0ull;
            int ra = 0, rb = 0;
            for (int t = 0; t < cnt; ++t) {
                unsigned long long kt = mk[wv][t];    // uniform LDS broadcast
                ra += (kt > Ka);
                rb += (kt > Kb);
            }
            if (l < cnt) mk[wv][ra] = Ka;
            if (64 + l < cnt) mk[wv][rb] = Kb;
        }

        // chunk 0 (members 0..63): ballot fixpoint == greedy
        unsigned long long kept0 = 0ull;
        {
            bool act = (l < cnt);
            unsigned long long myk = act ? mk[wv][l] : 0ull;
            int ii = act ? (int)(~(unsigned int)myk) : 0;
            float4 a = lbox[ii];
            float aarea = (a.z - a.x) * (a.w - a.y);

            unsigned long long colmask = 0ull;
            int tend = min(64, cnt);
            for (int t = 0; t < tend; ++t) {
                int it = (int)(~(unsigned int)mk[wv][t]);
                float4 tb = lbox[it];                 // uniform LDS broadcast
                if (t < l && act && iou_gt_thr(a, aarea, tb)) colmask |= (1ull << t);
            }

            unsigned long long kept = __ballot(act);
            while (true) {
                bool alive = act && ((colmask & kept) == 0ull);
                unsigned long long k2m = __ballot(alive);
                if (k2m == kept) break;
                kept = k2m;
            }
            kept0 = kept;
            bool alive = act && ((colmask & kept0) == 0ull);
            if (alive) keptflag[ii] = 1;              // row owned by exactly one class
        }

        // chunk 1 (members 64..cnt-1): rare (cnt>64)
        if (cnt > 64) {
            int m = 64 + l;
            bool act = (m < cnt);
            unsigned long long myk = act ? mk[wv][m] : 0ull;
            int ii = act ? (int)(~(unsigned int)myk) : 0;
            float4 a = lbox[ii];
            float aarea = (a.z - a.x) * (a.w - a.y);

            bool presup = false;
            for (int t = 0; t < 64; ++t) {
                if ((kept0 >> t) & 1ull) {
                    int it = (int)(~(unsigned int)mk[wv][t]);
                    if (act && iou_gt_thr(a, aarea, lbox[it])) presup = true;
                }
            }
            unsigned long long colmask = 0ull;
            for (int t = 64; t < cnt; ++t) {
                int it = (int)(~(unsigned int)mk[wv][t]);
                float4 tb = lbox[it];
                if ((t - 64) < l && act && iou_gt_thr(a, aarea, tb)) colmask |= (1ull << (t - 64));
            }
            bool pre = act && !presup;
            unsigned long long kept = __ballot(pre);
            while (true) {
                bool alive = pre && ((colmask & kept) == 0ull);
                unsigned long long k2m = __ballot(alive);
                if (k2m == kept) break;
                kept = k2m;
            }
            bool alive = pre && ((colmask & kept) == 0ull);
            if (alive) keptflag[ii] = 1;
        }
    }
    __syncthreads();

    // ---- compact kept keys into klist (aliases mk; NMS phase is done) ----
    unsigned long long* klist = &mk[0][0];            // 2048 u64
    for (int ch = wv; ch < 32; ch += 16) {
        int i = ch * 64 + l;
        bool pred = (i < NN) && keptflag[i];
        unsigned long long mask = __ballot(pred);
        int c2 = __popcll(mask);
        int base = 0;
        if (l == 0 && c2) base = atomicAdd(&Tcnt, c2);
        base = __shfl(base, 0);
        if (pred) klist[base + __popcll(mask & ((1ull << l) - 1ull))] = mkey(lsc[i], i);
    }
    __syncthreads();
    const int T = Tcnt;

    // ---- top-100 by rank-count over kept keys; write output rows ----
    for (int s = tid; s < T; s += 1024) {
        unsigned long long myk = klist[s];
        int r = 0;
        for (int t = 0; t < T; ++t) r += (klist[t] > myk);
        if (r < MAXI) {
            int i = (int)(~(unsigned int)myk);
            float4 bx = lbox[i];
            float* o = out + ((size_t)b * MAXI + r) * 6;
            o[0] = bx.x; o[1] = bx.y; o[2] = bx.z; o[3] = bx.w;
            o[4] = (float)lcl[i];
            o[5] = __uint_as_float((unsigned int)(myk >> 32));
        }
    }
    for (int r = T + tid; r < MAXI; r += 1024) {
        float* o = out + ((size_t)b * MAXI + r) * 6;
        #pragma unroll
        for (int q = 0; q < 6; ++q) o[q] = 0.f;
    }
}

extern "C" void kernel_launch(void* const* d_in, const int* in_sizes, int n_in,
                              void* d_out, int out_size, void* d_ws, size_t ws_size,
                              hipStream_t stream) {
    const float* rois   = (const float*)d_in[0];
    const float* probs  = (const float*)d_in[1];
    const float* deltas = (const float*)d_in[2];
    float* outp = (float*)d_out;

    char* ws = (char*)d_ws;
    float* boxes = (float*)(ws + 0);
    float* sc    = (float*)(ws + 256000);
    int*   cls   = (int*)  (ws + 320000);

    {
        int blocks = (BB * NN * 64) / 256;   // one wave per ROI, exact
        kA_refine<<<blocks, 256, 0, stream>>>(rois, probs, deltas, boxes, sc, cls);
    }
    {
        kB_nms<<<BB, 1024, 0, stream>>>(boxes, sc, cls, outp);
    }
}

// Round 8
// 65.451 us; speedup vs baseline: 3.1612x; 1.5270x over previous
//
#include <hip/hip_runtime.h>
#include <math.h>

#define BB 8
#define NN 2000
#define CC 81
#define MAXI 100
#define MCLS 128            // per-class member cap (mean ~25, sd ~5 -> 128 is +21 sd)
#define KLCAP 2048          // per-batch kept-list capacity (kept <= 2000)

static constexpr float kMinConf = 0.7f;
static constexpr float kNmsThr  = 0.3f;

// ---------------- workspace layout (bytes) ----------------
// boxes : [0,      256000)   BN*4 f32 (refined, clipped)
// sc    : [256000, 320000)   BN f32   (raw max score)
// cls   : [320000, 384000)   BN i32   (argmax class; 0 if invalid)
// kcnt  : [384000, 384064)   8 i32 (+pad)
// klist : [384064, 515136)   8*2048 u64 kept keys (unordered)

// member key: (score bits << 32) | ~idx. Valid scores are positive floats so
// u32 compare == float compare; key desc == (score desc, idx asc) == the
// reference's stable descending argsort. idx = ~(u32)key.
__device__ __forceinline__ unsigned long long mkey(float s, int i) {
    return ((unsigned long long)__float_as_uint(s) << 32) | (unsigned int)(~(unsigned int)i);
}

__device__ __forceinline__ bool iou_gt_thr(float4 a, float aarea, float4 t) {
    float iy1 = fmaxf(a.x, t.x), ix1 = fmaxf(a.y, t.y);
    float iy2 = fminf(a.z, t.z), ix2 = fminf(a.w, t.w);
    float inter = fmaxf(iy2 - iy1, 0.f) * fmaxf(ix2 - ix1, 0.f);
    float tarea = (t.z - t.x) * (t.w - t.y);
    float uni = fmaxf(aarea + tarea - inter, 1e-12f);
    return inter > kNmsThr * uni;
}

// ---- kA: wave-per-ROI argmax + box refine; also zero out[] and kcnt[] ----
__global__ void kA_refine(const float* __restrict__ rois,
                          const float* __restrict__ probs,
                          const float* __restrict__ deltas,
                          float* __restrict__ boxes,
                          float* __restrict__ sc,
                          int* __restrict__ cls,
                          int* __restrict__ kcnt,
                          float* __restrict__ outz) {
    int gtid = blockIdx.x * blockDim.x + threadIdx.x;
    if (gtid < BB * MAXI * 6) outz[gtid] = 0.f;      // pre-zero output
    if (gtid < BB) kcnt[gtid] = 0;

    int wid = gtid >> 6;                // one wave per ROI
    int l = gtid & 63;

    const float* p = probs + (size_t)wid * CC;
    float v1 = p[l];                    // l < 64 < 81 always valid
    int   i1 = l;
    int   c2 = l + 64;
    float v2 = (c2 < CC) ? p[c2] : -1.0f;   // probs in [0,1)
    float bv; int bi;
    if (v2 > v1) { bv = v2; bi = c2; } else { bv = v1; bi = i1; }

    #pragma unroll
    for (int off = 32; off; off >>= 1) {
        float ov = __shfl_xor(bv, off);
        int   oi = __shfl_xor(bi, off);
        if (ov > bv || (ov == bv && oi < bi)) { bv = ov; bi = oi; }
    }

    if (l == 0) {
        const float4 dl = *(const float4*)(deltas + ((size_t)wid * CC + bi) * 4);
        float dy = dl.x * 0.1f, dx = dl.y * 0.1f, dh = dl.z * 0.2f, dw = dl.w * 0.2f;
        const float4 r = *(const float4*)(rois + (size_t)wid * 4);
        float y1 = r.x, x1 = r.y, y2 = r.z, x2 = r.w;
        float h = y2 - y1, w = x2 - x1;
        float cy = y1 + 0.5f * h + dy * h;
        float cx = x1 + 0.5f * w + dx * w;
        float h2 = h * expf(dh);
        float w2 = w * expf(dw);
        float oy1 = fminf(fmaxf(cy - 0.5f * h2, 0.f), 1.f);
        float ox1 = fminf(fmaxf(cx - 0.5f * w2, 0.f), 1.f);
        float oy2 = fminf(fmaxf(cy + 0.5f * h2, 0.f), 1.f);
        float ox2 = fminf(fmaxf(cx + 0.5f * w2, 0.f), 1.f);
        bool valid = (bi > 0) && (bv >= kMinConf);
        float4 bx; bx.x = oy1; bx.y = ox1; bx.z = oy2; bx.w = ox2;
        ((float4*)boxes)[wid] = bx;
        sc[wid] = bv;
        cls[wid] = valid ? bi : 0;      // cls==0 encodes "invalid"
    }
}

// ---- kB: one wave per (batch,class). Collect members (coalesced cls scan +
// ballot), in-wave stable rank sort, ballot-fixpoint greedy NMS (== greedy,
// validated), append kept keys to per-batch global list. ----
__global__ void __launch_bounds__(64) kB_nms(
        const float* __restrict__ boxes,
        const float* __restrict__ sc,
        const int* __restrict__ cls,
        int* __restrict__ kcnt,
        unsigned long long* __restrict__ klist) {
    const int p = blockIdx.x;
    const int b = p / (CC - 1);
    const int c = p % (CC - 1) + 1;     // classes 1..80
    const int l = threadIdx.x;

    __shared__ unsigned long long mk[MCLS];
    __shared__ float4 mbox[MCLS];

    const int* cl = cls + (size_t)b * NN;
    const float* ssc = sc + (size_t)b * NN;
    const float4* bxs = (const float4*)boxes + (size_t)b * NN;

    // collect members of class c in row order (coalesced scan + ballot)
    int cnt = 0;
    for (int ch = 0; ch < 32; ++ch) {
        int i = ch * 64 + l;
        int ci = (i < NN) ? cl[i] : 0;
        bool pred = (ci == c);
        unsigned long long mask = __ballot(pred);
        if (pred) {
            int pos = cnt + __popcll(mask & ((1ull << l) - 1ull));
            if (pos < MCLS) mk[pos] = mkey(ssc[i], i);
        }
        cnt += __popcll(mask);
    }
    if (cnt > MCLS) cnt = MCLS;
    if (cnt == 0) return;

    // in-wave stable rank sort by key desc (keys unique; lockstep wave =>
    // all rank-loop reads complete before the scatter stores issue)
    {
        unsigned long long Ka = (l < cnt) ? mk[l] : 0ull;
        unsigned long long Kb = (64 + l < cnt) ? mk[64 + l] : 0ull;
        int ra = 0, rb = 0;
        for (int t = 0; t < cnt; ++t) {
            unsigned long long kt = mk[t];
            ra += (kt > Ka);
            rb += (kt > Kb);
        }
        if (l < cnt) mk[ra] = Ka;
        if (64 + l < cnt) mk[rb] = Kb;
    }

    // fetch member boxes (sorted order)
    for (int t = l; t < cnt; t += 64) {
        int i = (int)(~(unsigned int)mk[t]);
        mbox[t] = bxs[i];
    }

    // chunk 0 (members 0..63): ballot fixpoint == greedy
    unsigned long long kept0 = 0ull, kept1 = 0ull;
    {
        bool act = (l < cnt);
        float4 a = mbox[act ? l : 0];
        float aarea = (a.z - a.x) * (a.w - a.y);

        unsigned long long colmask = 0ull;
        int tend = min(64, cnt);
        for (int t = 0; t < tend; ++t) {
            float4 tb = mbox[t];                      // uniform LDS broadcast
            if (t < l && act && iou_gt_thr(a, aarea, tb)) colmask |= (1ull << t);
        }

        unsigned long long kept = __ballot(act);
        while (true) {
            bool alive = act && ((colmask & kept) == 0ull);
            unsigned long long k2m = __ballot(alive);
            if (k2m == kept) break;
            kept = k2m;
        }
        kept0 = kept;
    }

    // chunk 1 (members 64..cnt-1): rare (cnt > 64)
    if (cnt > 64) {
        int m = 64 + l;
        bool act = (m < cnt);
        float4 a = mbox[act ? m : 0];
        float aarea = (a.z - a.x) * (a.w - a.y);

        bool presup = false;
        for (int t = 0; t < 64; ++t) {
            if ((kept0 >> t) & 1ull) {
                if (act && iou_gt_thr(a, aarea, mbox[t])) presup = true;
            }
        }
        unsigned long long colmask = 0ull;
        for (int t = 64; t < cnt; ++t) {
            float4 tb = mbox[t];
            if ((t - 64) < l && act && iou_gt_thr(a, aarea, tb)) colmask |= (1ull << (t - 64));
        }
        bool pre = act && !presup;
        unsigned long long kept = __ballot(pre);
        while (true) {
            bool alive = pre && ((colmask & kept) == 0ull);
            unsigned long long k2m = __ballot(alive);
            if (k2m == kept) break;
            kept = k2m;
        }
        kept1 = kept;
    }

    // append kept keys to per-batch list (one atomic per wave)
    int nk0 = __popcll(kept0), nk1 = __popcll(kept1);
    int base;
    if (l == 0) base = atomicAdd(&kcnt[b], nk0 + nk1);
    base = __shfl(base, 0);
    unsigned long long* kl = klist + (size_t)b * KLCAP;
    if ((kept0 >> l) & 1ull)
        kl[base + __popcll(kept0 & ((1ull << l) - 1ull))] = mk[l];
    if (cnt > 64 && ((kept1 >> l) & 1ull))
        kl[base + nk0 + __popcll(kept1 & ((1ull << l) - 1ull))] = mk[64 + l];
}

// ---- kC: per-batch top-100 via histogram threshold + candidate rank-count ----
__global__ void __launch_bounds__(256) kC_emit(
        const int* __restrict__ kcnt,
        const unsigned long long* __restrict__ klist,
        const float* __restrict__ boxes,
        const float* __restrict__ sc,
        const int* __restrict__ cls,
        float* __restrict__ out) {
    const int b = blockIdx.x;
    const int tid = threadIdx.x;
    const int l = tid & 63, wv = tid >> 6;

    __shared__ unsigned long long keys[KLCAP];        // 16 KB
    __shared__ unsigned long long cand[512];          //  4 KB
    __shared__ int hist[256];
    __shared__ int tbsh, candn;

    int T = kcnt[b];
    if (T > KLCAP) T = KLCAP;

    for (int t = tid; t < T; t += 256) keys[t] = klist[(size_t)b * KLCAP + t];
    hist[tid] = 0;
    if (tid == 0) candn = 0;
    __syncthreads();
    if (T == 0) return;                               // out pre-zeroed by kA

    // histogram on score-bucket. All kept scores are in [0.7, 1.0) (>= MIN_CONF,
    // uniform < 1) -> same exponent (126) -> mantissa bits monotone in score.
    // bucket = (float_bits >> 15) & 0xFF == (key >> 47) & 0xFF, monotone.
    for (int t = tid; t < T; t += 256)
        atomicAdd(&hist[(int)((keys[t] >> 47) & 0xFF)], 1);
    __syncthreads();

    // wave 0: find threshold bucket tb (smallest b' with count(buckets >= b') >= 100)
    if (wv == 0) {
        int cum = 0, tb = 0, done = 0;
        for (int chunk = 3; chunk >= 0 && !done; --chunk) {
            int bkt = chunk * 64 + (63 - l);          // lane 0 = highest bucket
            int s = hist[bkt];
            #pragma unroll
            for (int off = 1; off < 64; off <<= 1) {  // inclusive scan, desc-bucket order
                int o = __shfl_up(s, off);
                if (l >= off) s += o;
            }
            int chunktot = __shfl(s, 63);
            if (cum + chunktot >= MAXI) {
                unsigned long long m = __ballot(cum + s >= MAXI);
                int lane = __ffsll((long long)m) - 1;
                tb = chunk * 64 + (63 - lane);
                done = 1;
            } else {
                cum += chunktot;
            }
        }
        if (l == 0) tbsh = done ? tb : 0;             // T < 100 -> all buckets
    }
    __syncthreads();
    const int tb = tbsh;

    // compact candidates (bucket >= tb). Non-candidates have strictly smaller
    // keys, so rank within candidates == global rank.
    for (int t = tid; t < ((T + 255) & ~255); t += 256) {
        bool pr = (t < T) && ((int)((keys[t] >> 47) & 0xFF) >= tb);
        unsigned long long m = __ballot(pr);
        int nb = __popcll(m);
        int basew;
        if (l == 0 && nb) basew = atomicAdd(&candn, nb);
        basew = __shfl(basew, 0);
        if (pr) {
            int pos = basew + __popcll(m & ((1ull << l) - 1ull));
            if (pos < 512) cand[pos] = keys[t];
        }
    }
    __syncthreads();
    int nc = candn;
    const unsigned long long* cset; int C;
    if (nc <= 512) { cset = cand; C = nc; }
    else          { cset = keys; C = T; }             // pathological fallback

    // exact rank-count among candidates; emit rank < 100
    for (int s = tid; s < C; s += 256) {
        unsigned long long myk = cset[s];
        int r = 0;
        for (int t = 0; t < C; ++t) r += (cset[t] > myk);
        if (r < MAXI) {
            int i = (int)(~(unsigned int)myk);
            float4 bx = ((const float4*)boxes)[(size_t)b * NN + i];
            float* o = out + ((size_t)b * MAXI + r) * 6;
            o[0] = bx.x; o[1] = bx.y; o[2] = bx.z; o[3] = bx.w;
            o[4] = (float)cls[(size_t)b * NN + i];
            o[5] = __uint_as_float((unsigned int)(myk >> 32));
        }
    }
}

extern "C" void kernel_launch(void* const* d_in, const int* in_sizes, int n_in,
                              void* d_out, int out_size, void* d_ws, size_t ws_size,
                              hipStream_t stream) {
    const float* rois   = (const float*)d_in[0];
    const float* probs  = (const float*)d_in[1];
    const float* deltas = (const float*)d_in[2];
    float* outp = (float*)d_out;

    char* ws = (char*)d_ws;
    float* boxes = (float*)(ws + 0);
    float* sc    = (float*)(ws + 256000);
    int*   cls   = (int*)  (ws + 320000);
    int*   kcnt  = (int*)  (ws + 384000);
    unsigned long long* klist = (unsigned long long*)(ws + 384064);

    {
        int blocks = (BB * NN * 64) / 256;   // one wave per ROI, exact
        kA_refine<<<blocks, 256, 0, stream>>>(rois, probs, deltas, boxes, sc, cls, kcnt, outp);
    }
    {
        kB_nms<<<BB * (CC - 1), 64, 0, stream>>>(boxes, sc, cls, kcnt, klist);
    }
    {
        kC_emit<<<BB, 256, 0, stream>>>(kcnt, klist, boxes, sc, cls, outp);
    }
}